// Round 3
// baseline (373.179 us; speedup 1.0000x reference)
//
#include <hip/hip_runtime.h>
#include <stdint.h>

typedef unsigned long long ULL;

// ---------------- prep kernels: pack weight signs into bit-words ----------------

// conv1 weight signs as float +-1 (576 elements)
__global__ void prep_sgn1(const float* __restrict__ w1, float* __restrict__ sgn1) {
    int t = blockIdx.x * 256 + threadIdx.x;
    if (t < 576) sgn1[t] = (w1[t] >= 0.f) ? 1.f : -1.f;
}

// conv2 weights: wb2[co*9+tap] bit ci = sign(w2[co][ci][tap])   (576 words)
// fc2 weights:   wbf2[n*32+k]  bit j  = sign(fc2w[n][k*64+j])   (320 words)
__global__ void prep_pack_small(const float* __restrict__ w2, const float* __restrict__ fc2w,
                                ULL* __restrict__ wb2, ULL* __restrict__ wbf2) {
    int wave = threadIdx.x >> 6, lane = threadIdx.x & 63;
    int W = blockIdx.x * 4 + wave;
    if (W < 576) {
        int co = W / 9, tap = W - co * 9;
        ULL wd = __ballot(w2[(co * 64 + lane) * 9 + tap] >= 0.f);
        if (lane == 0) wb2[W] = wd;
    } else if (W < 576 + 320) {
        int idx = W - 576;
        int n = idx >> 5, k = idx & 31;
        ULL wd = __ballot(fc2w[n * 2048 + k * 64 + lane] >= 0.f);
        if (lane == 0) wbf2[idx] = wd;
    }
}

// fc1 weights transposed: wbT[p*2048 + n] bit c = sign(fc1w[n][c*49+p])
__global__ void prep_pack_fc1(const float* __restrict__ fc1w, ULL* __restrict__ wbT) {
    int wave = threadIdx.x >> 6, lane = threadIdx.x & 63;
    int W = blockIdx.x * 4 + wave;          // 8192 waves total
    int n = W >> 2, pq = W & 3;
    int p0 = pq * 13, p1 = (p0 + 13 < 49) ? p0 + 13 : 49;
    const float* row = fc1w + (size_t)n * 3136 + lane * 49;
    for (int p = p0; p < p1; ++p) {
        ULL wd = __ballot(row[p] >= 0.f);
        if (lane == 0) wbT[p * 2048 + n] = wd;
    }
}

// ---------------- k1: conv1 + maxpool + bn1 + binarize -> qact1 bits ----------------
// one block per sample; thread t<196 owns pool position (py,px), loops 64 out channels
__global__ __launch_bounds__(256) void k1_conv1(const float* __restrict__ x,
        const float* __restrict__ sgn1, const float* __restrict__ b1,
        const float* __restrict__ g, const float* __restrict__ be,
        const float* __restrict__ mu, const float* __restrict__ va,
        ULL* __restrict__ qact1) {
    __shared__ double invd[64], cd[64], bd[64];
    int b = blockIdx.x, t = threadIdx.x;
    if (t < 64) {
        double iv = (double)g[t] / sqrt((double)va[t] + 1e-5);
        invd[t] = iv;
        cd[t]  = (double)be[t] - (double)mu[t] * iv;
        bd[t]  = (double)b1[t];
    }
    __syncthreads();
    if (t < 196) {
        int py = t / 14, px = t - py * 14;
        int y0 = 2 * py - 1, x0 = 2 * px - 1;
        float patch[4][4];
        const float* xb = x + (size_t)b * 784;
        #pragma unroll
        for (int r = 0; r < 4; ++r) {
            int y = y0 + r;
            #pragma unroll
            for (int c = 0; c < 4; ++c) {
                int xx = x0 + c;
                patch[r][c] = (y >= 0 && y < 28 && xx >= 0 && xx < 28) ? xb[y * 28 + xx] : 0.f;
            }
        }
        ULL mask = 0;
        for (int co = 0; co < 64; ++co) {
            const float* s = sgn1 + co * 9;   // wave-uniform -> scalar loads
            float a00 = 0.f, a01 = 0.f, a10 = 0.f, a11 = 0.f;
            #pragma unroll
            for (int ky = 0; ky < 3; ++ky) {
                #pragma unroll
                for (int kx = 0; kx < 3; ++kx) {
                    float sv = s[ky * 3 + kx];
                    a00 = fmaf(patch[ky][kx],         sv, a00);
                    a01 = fmaf(patch[ky][kx + 1],     sv, a01);
                    a10 = fmaf(patch[ky + 1][kx],     sv, a10);
                    a11 = fmaf(patch[ky + 1][kx + 1], sv, a11);
                }
            }
            float m = fmaxf(fmaxf(a00, a01), fmaxf(a10, a11));
            double v  = (double)m + bd[co];
            double tt = v * invd[co] + cd[co];
            mask |= (ULL)(tt >= 0.0) << co;
        }
        qact1[(size_t)b * 196 + t] = mask;
    }
}

// ---------------- k2: conv2 + maxpool + bn2 + binarize -> qact2 bits ----------------
// one block per sample; lane = out channel, wave strides over 49 pool positions
__global__ __launch_bounds__(256) void k2_conv2(const ULL* __restrict__ qact1,
        const ULL* __restrict__ wb2, const float* __restrict__ b2,
        const float* __restrict__ g, const float* __restrict__ be,
        const float* __restrict__ mu, const float* __restrict__ va,
        ULL* __restrict__ qact2) {
    __shared__ ULL a_s[196];
    __shared__ ULL w_s[576];
    __shared__ double invd[64], cd[64], bd[64];
    int b = blockIdx.x, t = threadIdx.x;
    int wave = t >> 6, lane = t & 63;
    if (t < 196) a_s[t] = qact1[(size_t)b * 196 + t];
    for (int i = t; i < 576; i += 256) w_s[i] = wb2[i];
    if (t < 64) {
        double iv = (double)g[t] / sqrt((double)va[t] + 1e-5);
        invd[t] = iv;
        cd[t]  = (double)be[t] - (double)mu[t] * iv;
        bd[t]  = (double)b2[t];
    }
    __syncthreads();
    ULL wk[9];
    #pragma unroll
    for (int k = 0; k < 9; ++k) wk[k] = w_s[lane * 9 + k];
    for (int p = wave; p < 49; p += 4) {
        int py = p / 7, px = p - py * 7;
        int m = -1000000;
        #pragma unroll
        for (int dy = 0; dy < 2; ++dy) {
            #pragma unroll
            for (int dx = 0; dx < 2; ++dx) {
                int y = 2 * py + dy, xx = 2 * px + dx;
                int acc = 0;
                #pragma unroll
                for (int ky = 0; ky < 3; ++ky) {
                    int ny = y + ky - 1;
                    if (ny < 0 || ny >= 14) continue;
                    #pragma unroll
                    for (int kx = 0; kx < 3; ++kx) {
                        int nx = xx + kx - 1;
                        if (nx < 0 || nx >= 14) continue;
                        acc += 64 - 2 * (int)__popcll(a_s[ny * 14 + nx] ^ wk[ky * 3 + kx]);
                    }
                }
                m = max(m, acc);
            }
        }
        double v  = (double)m + bd[lane];
        double tt = v * invd[lane] + cd[lane];
        ULL word = __ballot(tt >= 0.0);
        if (lane == 0) qact2[(size_t)b * 49 + p] = word;
    }
}

// ---------------- k3: fc1 + bn3 + binarize -> hbits ----------------
// block = 16 samples x 4 n-groups (wave = 64 outputs), weights reused 16x from L2
__global__ __launch_bounds__(256) void k3_fc1(const ULL* __restrict__ qact2,
        const ULL* __restrict__ wbT, const float* __restrict__ fb,
        const float* __restrict__ g, const float* __restrict__ be,
        const float* __restrict__ mu, const float* __restrict__ va,
        ULL* __restrict__ hbits) {
    __shared__ ULL xs[784];   // 16 samples x 49 words
    int t = threadIdx.x, wave = t >> 6, lane = t & 63;
    int b0 = blockIdx.x * 16;
    int gidx = blockIdx.y * 4 + wave;   // 0..31
    int n = gidx * 64 + lane;
    for (int i = t; i < 784; i += 256) xs[i] = qact2[(size_t)b0 * 49 + i];
    double iv   = (double)g[n] / sqrt((double)va[n] + 1e-5);
    double cc   = (double)be[n] - (double)mu[n] * iv;
    double bias = (double)fb[n];
    __syncthreads();
    int acc[16];
    #pragma unroll
    for (int i = 0; i < 16; ++i) acc[i] = 0;
    for (int p = 0; p < 49; ++p) {
        ULL w = wbT[p * 2048 + n];
        #pragma unroll
        for (int i = 0; i < 16; ++i)
            acc[i] += (int)__popcll(xs[i * 49 + p] ^ w);
    }
    #pragma unroll
    for (int i = 0; i < 16; ++i) {
        int dot = 3136 - 2 * acc[i];
        double tt = ((double)dot + bias) * iv + cc;
        ULL word = __ballot(tt >= 0.0);
        if (lane == 0) hbits[(size_t)(b0 + i) * 32 + gidx] = word;
    }
}

// ---------------- k4: fc2 + scale ----------------
__global__ __launch_bounds__(256) void k4_fc2(const ULL* __restrict__ hbits,
        const ULL* __restrict__ wbf2, const float* __restrict__ b2,
        const float* __restrict__ scale, float* __restrict__ out, int total) {
    int gid = blockIdx.x * 256 + threadIdx.x;
    if (gid >= total) return;
    int b = gid / 10, n = gid - b * 10;
    const ULL* h = hbits + (size_t)b * 32;
    const ULL* w = wbf2 + n * 32;
    int acc = 0;
    #pragma unroll
    for (int k = 0; k < 32; ++k) acc += (int)__popcll(h[k] ^ w[k]);
    int dot = 2048 - 2 * acc;
    double v = ((double)dot + (double)b2[n]) * (double)scale[0];
    out[gid] = (float)v;
}

// ---------------- launch ----------------
extern "C" void kernel_launch(void* const* d_in, const int* in_sizes, int n_in,
                              void* d_out, int out_size, void* d_ws, size_t ws_size,
                              hipStream_t stream) {
    const float* x      = (const float*)d_in[0];
    const float* w1     = (const float*)d_in[1];
    const float* b1     = (const float*)d_in[2];
    const float* w2     = (const float*)d_in[3];
    const float* b2     = (const float*)d_in[4];
    const float* fc1w   = (const float*)d_in[5];
    const float* fc1b   = (const float*)d_in[6];
    const float* fc2w   = (const float*)d_in[7];
    const float* fc2b   = (const float*)d_in[8];
    const float* g1 = (const float*)d_in[9],  *be1 = (const float*)d_in[10],
               *mu1 = (const float*)d_in[11], *va1 = (const float*)d_in[12];
    const float* g2 = (const float*)d_in[13], *be2 = (const float*)d_in[14],
               *mu2 = (const float*)d_in[15], *va2 = (const float*)d_in[16];
    const float* g3 = (const float*)d_in[17], *be3 = (const float*)d_in[18],
               *mu3 = (const float*)d_in[19], *va3 = (const float*)d_in[20];
    const float* scale = (const float*)d_in[21];
    float* out = (float*)d_out;

    int B = in_sizes[0] / 784;   // 4096

    // workspace layout (8B aligned)
    char* ws = (char*)d_ws;
    ULL* qact1 = (ULL*)(ws);                              // B*196 words
    ULL* qact2 = (ULL*)(ws + (size_t)B * 196 * 8);        // B*49 words
    ULL* hbits = (ULL*)(ws + (size_t)B * 245 * 8);        // B*32 words
    char* wsw  = ws + (size_t)B * 277 * 8;
    ULL* wb2   = (ULL*)(wsw);                             // 576 words
    ULL* wbT   = (ULL*)(wsw + 576 * 8);                   // 49*2048 words
    ULL* wbf2  = (ULL*)(wsw + 576 * 8 + 49 * 2048 * 8);   // 320 words
    float* sgn1 = (float*)(wsw + 576 * 8 + 49 * 2048 * 8 + 320 * 8); // 576 floats

    prep_sgn1<<<3, 256, 0, stream>>>(w1, sgn1);
    prep_pack_small<<<224, 256, 0, stream>>>(w2, fc2w, wb2, wbf2);
    prep_pack_fc1<<<2048, 256, 0, stream>>>(fc1w, wbT);

    k1_conv1<<<B, 256, 0, stream>>>(x, sgn1, b1, g1, be1, mu1, va1, qact1);
    k2_conv2<<<B, 256, 0, stream>>>(qact1, wb2, b2, g2, be2, mu2, va2, qact2);
    k3_fc1<<<dim3(B / 16, 8), 256, 0, stream>>>(qact2, wbT, fc1b, g3, be3, mu3, va3, hbits);
    int total = B * 10;
    k4_fc2<<<(total + 255) / 256, 256, 0, stream>>>(hbits, wbf2, fc2b, scale, out, total);
}

// Round 6
// 339.103 us; speedup vs baseline: 1.1005x; 1.1005x over previous
//
#include <hip/hip_runtime.h>
#include <stdint.h>

typedef unsigned long long ULL;

// ---------------- prep kernels: pack weight signs into bit-words ----------------

// conv1 weight signs as float +-1 (576 elements)
__global__ void prep_sgn1(const float* __restrict__ w1, float* __restrict__ sgn1) {
    int t = blockIdx.x * 256 + threadIdx.x;
    if (t < 576) sgn1[t] = (w1[t] >= 0.f) ? 1.f : -1.f;
}

// conv2 weights: wb2[co*9+tap] bit ci = sign(w2[co][ci][tap])   (576 words)
// fc2 weights:   wbf2[n*32+k]  bit j  = sign(fc2w[n][k*64+j])   (320 words)
__global__ void prep_pack_small(const float* __restrict__ w2, const float* __restrict__ fc2w,
                                ULL* __restrict__ wb2, ULL* __restrict__ wbf2) {
    int wave = threadIdx.x >> 6, lane = threadIdx.x & 63;
    int W = blockIdx.x * 4 + wave;
    if (W < 576) {
        int co = W / 9, tap = W - co * 9;
        ULL wd = __ballot(w2[(co * 64 + lane) * 9 + tap] >= 0.f);
        if (lane == 0) wb2[W] = wd;
    } else if (W < 576 + 320) {
        int idx = W - 576;
        int n = idx >> 5, k = idx & 31;
        ULL wd = __ballot(fc2w[n * 2048 + k * 64 + lane] >= 0.f);
        if (lane == 0) wbf2[idx] = wd;
    }
}

// fc1 weights transposed: wbT[p*2048 + n] bit c = sign(fc1w[n][c*49+p])
// v2: stage 4 contiguous rows (one block = 4 n's) in LDS coalesced, ballot from LDS.
// GRID MUST BE 512 blocks (512*4 = 2048 rows).
__global__ __launch_bounds__(256) void prep_pack_fc1(const float* __restrict__ fc1w,
                                                     ULL* __restrict__ wbT) {
    __shared__ float rows[4 * 3136];
    int t = threadIdx.x;
    const float* src = fc1w + (size_t)blockIdx.x * 4 * 3136;
    for (int i = t; i < 4 * 3136; i += 256) rows[i] = src[i];
    __syncthreads();
    int wave = t >> 6, lane = t & 63;
    int n = blockIdx.x * 4 + wave;
    const float* r = rows + wave * 3136 + lane * 49;   // stride 49 % 32 = 17 -> 2-way, free
    for (int p = 0; p < 49; ++p) {
        ULL wd = __ballot(r[p] >= 0.f);
        if (lane == 0) wbT[p * 2048 + n] = wd;
    }
}

// ---------------- k1: conv1 + maxpool + bn1 + binarize -> qact1 bits ----------------
// one block per sample; thread t<196 owns pool position (py,px), loops 64 out channels
__global__ __launch_bounds__(256) void k1_conv1(const float* __restrict__ x,
        const float* __restrict__ sgn1, const float* __restrict__ b1,
        const float* __restrict__ g, const float* __restrict__ be,
        const float* __restrict__ mu, const float* __restrict__ va,
        ULL* __restrict__ qact1) {
    __shared__ double invd[64], cd[64], bd[64];
    int b = blockIdx.x, t = threadIdx.x;
    if (t < 64) {
        double iv = (double)g[t] / sqrt((double)va[t] + 1e-5);
        invd[t] = iv;
        cd[t]  = (double)be[t] - (double)mu[t] * iv;
        bd[t]  = (double)b1[t];
    }
    __syncthreads();
    if (t < 196) {
        int py = t / 14, px = t - py * 14;
        int y0 = 2 * py - 1, x0 = 2 * px - 1;
        float patch[4][4];
        const float* xb = x + (size_t)b * 784;
        #pragma unroll
        for (int r = 0; r < 4; ++r) {
            int y = y0 + r;
            #pragma unroll
            for (int c = 0; c < 4; ++c) {
                int xx = x0 + c;
                patch[r][c] = (y >= 0 && y < 28 && xx >= 0 && xx < 28) ? xb[y * 28 + xx] : 0.f;
            }
        }
        ULL mask = 0;
        for (int co = 0; co < 64; ++co) {
            const float* s = sgn1 + co * 9;   // wave-uniform -> scalar loads
            float a00 = 0.f, a01 = 0.f, a10 = 0.f, a11 = 0.f;
            #pragma unroll
            for (int ky = 0; ky < 3; ++ky) {
                #pragma unroll
                for (int kx = 0; kx < 3; ++kx) {
                    float sv = s[ky * 3 + kx];
                    a00 = fmaf(patch[ky][kx],         sv, a00);
                    a01 = fmaf(patch[ky][kx + 1],     sv, a01);
                    a10 = fmaf(patch[ky + 1][kx],     sv, a10);
                    a11 = fmaf(patch[ky + 1][kx + 1], sv, a11);
                }
            }
            float m = fmaxf(fmaxf(a00, a01), fmaxf(a10, a11));
            double v  = (double)m + bd[co];
            double tt = v * invd[co] + cd[co];
            mask |= (ULL)(tt >= 0.0) << co;
        }
        qact1[(size_t)b * 196 + t] = mask;
    }
}

// ---------------- k2 v2: conv2 + maxpool + bn2 + binarize -> qact2 bits ----------------
// one block per sample, 7 waves; wave = pool row; lane = out channel.
// Zero-padded 16x16 LDS word array (no bounds branches); pad contribution removed
// exactly via per-lane corrections; sliding 4x4 register window (8 broadcast
// ds_read_b64 per pool position instead of 36).
__global__ __launch_bounds__(448) void k2_conv2(const ULL* __restrict__ qact1,
        const ULL* __restrict__ wb2, const float* __restrict__ b2,
        const float* __restrict__ g, const float* __restrict__ be,
        const float* __restrict__ mu, const float* __restrict__ va,
        ULL* __restrict__ qact2) {
    __shared__ ULL ap[16][16];
    int b = blockIdx.x, t = threadIdx.x;
    int pr = t >> 6, lane = t & 63;          // pr = pool row 0..6
    if (t < 256) ap[t >> 4][t & 15] = 0ULL;
    __syncthreads();
    if (t < 196) ap[1 + t / 14][1 + t % 14] = qact1[(size_t)b * 196 + t];

    // per-lane (= output channel) weights and constants
    ULL wk[9];
    #pragma unroll
    for (int k = 0; k < 9; ++k) wk[k] = wb2[lane * 9 + k];
    int pw[9];
    #pragma unroll
    for (int k = 0; k < 9; ++k) pw[k] = 64 - 2 * (int)__popcll(wk[k]);
    double iv   = (double)g[lane] / sqrt((double)va[lane] + 1e-5);
    double cc   = (double)be[lane] - (double)mu[lane] * iv;
    double bias = (double)b2[lane];

    // padding corrections: corr[j][cls], j = conv-row within pool pair, cls 0=L,1=M,2=R
    int corr[2][3];
    #pragma unroll
    for (int j = 0; j < 2; ++j) {
        bool tpad = (pr == 0 && j == 0);
        bool bpad = (pr == 6 && j == 1);
        #pragma unroll
        for (int cls = 0; cls < 3; ++cls) {
            int cacc = 0;
            #pragma unroll
            for (int r = 0; r < 3; ++r) {
                #pragma unroll
                for (int k = 0; k < 3; ++k) {
                    bool pad = (r == 0 && tpad) || (r == 2 && bpad) ||
                               (k == 0 && cls == 0) || (k == 2 && cls == 2);
                    if (pad) cacc += pw[r * 3 + k];
                }
            }
            corr[j][cls] = cacc;
        }
    }
    __syncthreads();

    // sliding window: win[r][c] = ap[2*pr + r][2*px + c], padded rows 2pr..2pr+3
    ULL win[4][4];
    #pragma unroll
    for (int r = 0; r < 4; ++r) {
        win[r][0] = ap[2 * pr + r][0];
        win[r][1] = ap[2 * pr + r][1];
    }
    for (int px = 0; px < 7; ++px) {
        #pragma unroll
        for (int r = 0; r < 4; ++r) {
            win[r][2] = ap[2 * pr + r][2 * px + 2];
            win[r][3] = ap[2 * pr + r][2 * px + 3];
        }
        int s00 = 0, s01 = 0, s10 = 0, s11 = 0;
        #pragma unroll
        for (int r = 0; r < 3; ++r) {
            #pragma unroll
            for (int k = 0; k < 3; ++k) {
                ULL w = wk[r * 3 + k];
                s00 += (int)__popcll(win[r][k]         ^ w);
                s01 += (int)__popcll(win[r][k + 1]     ^ w);
                s10 += (int)__popcll(win[r + 1][k]     ^ w);
                s11 += (int)__popcll(win[r + 1][k + 1] ^ w);
            }
        }
        int clsL = (px == 0) ? 0 : 1, clsR = (px == 6) ? 2 : 1;
        int d00 = 576 - 2 * s00 - corr[0][clsL];
        int d01 = 576 - 2 * s01 - corr[0][clsR];
        int d10 = 576 - 2 * s10 - corr[1][clsL];
        int d11 = 576 - 2 * s11 - corr[1][clsR];
        int m = max(max(d00, d01), max(d10, d11));
        double tt = ((double)m + bias) * iv + cc;
        ULL word = __ballot(tt >= 0.0);
        if (lane == 0) qact2[(size_t)b * 49 + pr * 7 + px] = word;
        #pragma unroll
        for (int r = 0; r < 4; ++r) {
            win[r][0] = win[r][2];
            win[r][1] = win[r][3];
        }
    }
}

// ---------------- k3: fc1 + bn3 + binarize -> hbits ----------------
// block = 16 samples x 4 n-groups (wave = 64 outputs), weights reused 16x from L2
__global__ __launch_bounds__(256) void k3_fc1(const ULL* __restrict__ qact2,
        const ULL* __restrict__ wbT, const float* __restrict__ fb,
        const float* __restrict__ g, const float* __restrict__ be,
        const float* __restrict__ mu, const float* __restrict__ va,
        ULL* __restrict__ hbits) {
    __shared__ ULL xs[784];   // 16 samples x 49 words
    int t = threadIdx.x, wave = t >> 6, lane = t & 63;
    int b0 = blockIdx.x * 16;
    int gidx = blockIdx.y * 4 + wave;   // 0..31
    int n = gidx * 64 + lane;
    for (int i = t; i < 784; i += 256) xs[i] = qact2[(size_t)b0 * 49 + i];
    double iv   = (double)g[n] / sqrt((double)va[n] + 1e-5);
    double cc   = (double)be[n] - (double)mu[n] * iv;
    double bias = (double)fb[n];
    __syncthreads();
    int acc[16];
    #pragma unroll
    for (int i = 0; i < 16; ++i) acc[i] = 0;
    for (int p = 0; p < 49; ++p) {
        ULL w = wbT[p * 2048 + n];
        #pragma unroll
        for (int i = 0; i < 16; ++i)
            acc[i] += (int)__popcll(xs[i * 49 + p] ^ w);
    }
    #pragma unroll
    for (int i = 0; i < 16; ++i) {
        int dot = 3136 - 2 * acc[i];
        double tt = ((double)dot + bias) * iv + cc;
        ULL word = __ballot(tt >= 0.0);
        if (lane == 0) hbits[(size_t)(b0 + i) * 32 + gidx] = word;
    }
}

// ---------------- k4: fc2 + scale ----------------
__global__ __launch_bounds__(256) void k4_fc2(const ULL* __restrict__ hbits,
        const ULL* __restrict__ wbf2, const float* __restrict__ b2,
        const float* __restrict__ scale, float* __restrict__ out, int total) {
    int gid = blockIdx.x * 256 + threadIdx.x;
    if (gid >= total) return;
    int b = gid / 10, n = gid - b * 10;
    const ULL* h = hbits + (size_t)b * 32;
    const ULL* w = wbf2 + n * 32;
    int acc = 0;
    #pragma unroll
    for (int k = 0; k < 32; ++k) acc += (int)__popcll(h[k] ^ w[k]);
    int dot = 2048 - 2 * acc;
    double v = ((double)dot + (double)b2[n]) * (double)scale[0];
    out[gid] = (float)v;
}

// ---------------- launch ----------------
extern "C" void kernel_launch(void* const* d_in, const int* in_sizes, int n_in,
                              void* d_out, int out_size, void* d_ws, size_t ws_size,
                              hipStream_t stream) {
    const float* x      = (const float*)d_in[0];
    const float* w1     = (const float*)d_in[1];
    const float* b1     = (const float*)d_in[2];
    const float* w2     = (const float*)d_in[3];
    const float* b2     = (const float*)d_in[4];
    const float* fc1w   = (const float*)d_in[5];
    const float* fc1b   = (const float*)d_in[6];
    const float* fc2w   = (const float*)d_in[7];
    const float* fc2b   = (const float*)d_in[8];
    const float* g1 = (const float*)d_in[9],  *be1 = (const float*)d_in[10],
               *mu1 = (const float*)d_in[11], *va1 = (const float*)d_in[12];
    const float* g2 = (const float*)d_in[13], *be2 = (const float*)d_in[14],
               *mu2 = (const float*)d_in[15], *va2 = (const float*)d_in[16];
    const float* g3 = (const float*)d_in[17], *be3 = (const float*)d_in[18],
               *mu3 = (const float*)d_in[19], *va3 = (const float*)d_in[20];
    const float* scale = (const float*)d_in[21];
    float* out = (float*)d_out;

    int B = in_sizes[0] / 784;   // 4096

    // workspace layout (8B aligned)
    char* ws = (char*)d_ws;
    ULL* qact1 = (ULL*)(ws);                              // B*196 words
    ULL* qact2 = (ULL*)(ws + (size_t)B * 196 * 8);        // B*49 words
    ULL* hbits = (ULL*)(ws + (size_t)B * 245 * 8);        // B*32 words
    char* wsw  = ws + (size_t)B * 277 * 8;
    ULL* wb2   = (ULL*)(wsw);                             // 576 words
    ULL* wbT   = (ULL*)(wsw + 576 * 8);                   // 49*2048 words
    ULL* wbf2  = (ULL*)(wsw + 576 * 8 + 49 * 2048 * 8);   // 320 words
    float* sgn1 = (float*)(wsw + 576 * 8 + 49 * 2048 * 8 + 320 * 8); // 576 floats

    prep_sgn1<<<3, 256, 0, stream>>>(w1, sgn1);
    prep_pack_small<<<224, 256, 0, stream>>>(w2, fc2w, wb2, wbf2);
    prep_pack_fc1<<<512, 256, 0, stream>>>(fc1w, wbT);   // 512 blocks x 4 rows = 2048

    k1_conv1<<<B, 256, 0, stream>>>(x, sgn1, b1, g1, be1, mu1, va1, qact1);
    k2_conv2<<<B, 448, 0, stream>>>(qact1, wb2, b2, g2, be2, mu2, va2, qact2);
    k3_fc1<<<dim3(B / 16, 8), 256, 0, stream>>>(qact2, wbT, fc1b, g3, be3, mu3, va3, hbits);
    int total = B * 10;
    k4_fc2<<<(total + 255) / 256, 256, 0, stream>>>(hbits, wbf2, fc2b, scale, out, total);
}

// Round 7
// 312.923 us; speedup vs baseline: 1.1926x; 1.0837x over previous
//
#include <hip/hip_runtime.h>
#include <stdint.h>

typedef unsigned long long ULL;

// ---------------- prep kernels: pack weight signs into bit-words ----------------

// conv1 weight signs as float +-1 (576 elements)
__global__ void prep_sgn1(const float* __restrict__ w1, float* __restrict__ sgn1) {
    int t = blockIdx.x * 256 + threadIdx.x;
    if (t < 576) sgn1[t] = (w1[t] >= 0.f) ? 1.f : -1.f;
}

// conv2 weights: wb2[co*9+tap] bit ci = sign(w2[co][ci][tap])   (576 words)
// fc2 weights:   wbf2[n*32+k]  bit j  = sign(fc2w[n][k*64+j])   (320 words)
__global__ void prep_pack_small(const float* __restrict__ w2, const float* __restrict__ fc2w,
                                ULL* __restrict__ wb2, ULL* __restrict__ wbf2) {
    int wave = threadIdx.x >> 6, lane = threadIdx.x & 63;
    int W = blockIdx.x * 4 + wave;
    if (W < 576) {
        int co = W / 9, tap = W - co * 9;
        ULL wd = __ballot(w2[(co * 64 + lane) * 9 + tap] >= 0.f);
        if (lane == 0) wb2[W] = wd;
    } else if (W < 576 + 320) {
        int idx = W - 576;
        int n = idx >> 5, k = idx & 31;
        ULL wd = __ballot(fc2w[n * 2048 + k * 64 + lane] >= 0.f);
        if (lane == 0) wbf2[idx] = wd;
    }
}

// fc1 weights transposed: wbT[p*2048 + n] bit c = sign(fc1w[n][c*49+p])
// stage 4 contiguous rows (one block = 4 n's) in LDS coalesced, ballot from LDS.
// GRID MUST BE 512 blocks (512*4 = 2048 rows).
__global__ __launch_bounds__(256) void prep_pack_fc1(const float* __restrict__ fc1w,
                                                     ULL* __restrict__ wbT) {
    __shared__ float rows[4 * 3136];
    int t = threadIdx.x;
    const float* src = fc1w + (size_t)blockIdx.x * 4 * 3136;
    for (int i = t; i < 4 * 3136; i += 256) rows[i] = src[i];
    __syncthreads();
    int wave = t >> 6, lane = t & 63;
    int n = blockIdx.x * 4 + wave;
    const float* r = rows + wave * 3136 + lane * 49;   // stride 49 % 32 = 17 -> 2-way, free
    for (int p = 0; p < 49; ++p) {
        ULL wd = __ballot(r[p] >= 0.f);
        if (lane == 0) wbT[p * 2048 + n] = wd;
    }
}

// ---------------- k1 v2: conv1 + maxpool + bn1 + binarize -> qact1 bits ----------------
// one block per sample, 7 waves; lane = output channel (weights + BN consts in REGISTERS);
// wave = pool row (rows w and w+7); image staged column-major zero-padded 30x30 in LDS;
// sliding 4x4 window, 2 float2-pair broadcast reads per new column; ballot packs the word.
__global__ __launch_bounds__(448) void k1_conv1(const float* __restrict__ x,
        const float* __restrict__ sgn1, const float* __restrict__ b1,
        const float* __restrict__ g, const float* __restrict__ be,
        const float* __restrict__ mu, const float* __restrict__ va,
        ULL* __restrict__ qact1) {
    __shared__ float limg[30 * 30];   // limg[(x+1)*30 + (y+1)], borders zero
    int b = blockIdx.x, t = threadIdx.x;
    int wave = t >> 6, lane = t & 63;
    for (int i = t; i < 900; i += 448) limg[i] = 0.f;
    __syncthreads();
    const float* xb = x + (size_t)b * 784;
    for (int i = t; i < 784; i += 448) {
        int y = i / 28, xx = i - y * 28;
        limg[(xx + 1) * 30 + (y + 1)] = xb[i];   // transposed store, ~2-way bank alias (free)
    }
    // per-lane (= output channel) weights and BN constants, loaded once
    float w[9];
    #pragma unroll
    for (int k = 0; k < 9; ++k) w[k] = sgn1[lane * 9 + k];
    double iv = (double)g[lane] / sqrt((double)va[lane] + 1e-5);
    double cd = (double)be[lane] - (double)mu[lane] * iv;
    double bd = (double)b1[lane];
    __syncthreads();

    #pragma unroll
    for (int rr = 0; rr < 2; ++rr) {
        int py = wave + rr * 7;           // pool row 0..13
        // window cols are lds cols 2px..2px+3, rows 2py..2py+3 (column-contiguous)
        float win[4][4];
        #pragma unroll
        for (int c = 0; c < 2; ++c) {
            const float2* cp = (const float2*)&limg[c * 30 + 2 * py];  // 8B-aligned: even offset
            float2 lo = cp[0], hi = cp[1];
            win[0][c] = lo.x; win[1][c] = lo.y; win[2][c] = hi.x; win[3][c] = hi.y;
        }
        for (int px = 0; px < 14; ++px) {
            #pragma unroll
            for (int c = 0; c < 2; ++c) {
                const float2* cp = (const float2*)&limg[(2 * px + 2 + c) * 30 + 2 * py];
                float2 lo = cp[0], hi = cp[1];
                win[0][2 + c] = lo.x; win[1][2 + c] = lo.y; win[2][2 + c] = hi.x; win[3][2 + c] = hi.y;
            }
            float a00 = 0.f, a01 = 0.f, a10 = 0.f, a11 = 0.f;
            #pragma unroll
            for (int ky = 0; ky < 3; ++ky) {
                #pragma unroll
                for (int kx = 0; kx < 3; ++kx) {
                    float sv = w[ky * 3 + kx];
                    a00 = fmaf(win[ky][kx],         sv, a00);
                    a01 = fmaf(win[ky][kx + 1],     sv, a01);
                    a10 = fmaf(win[ky + 1][kx],     sv, a10);
                    a11 = fmaf(win[ky + 1][kx + 1], sv, a11);
                }
            }
            float m = fmaxf(fmaxf(a00, a01), fmaxf(a10, a11));
            double v  = (double)m + bd;
            double tt = v * iv + cd;
            ULL word = __ballot(tt >= 0.0);
            if (lane == 0) qact1[(size_t)b * 196 + py * 14 + px] = word;
            #pragma unroll
            for (int r = 0; r < 4; ++r) {
                win[r][0] = win[r][2];
                win[r][1] = win[r][3];
            }
        }
    }
}

// ---------------- k2 v2: conv2 + maxpool + bn2 + binarize -> qact2 bits ----------------
// one block per sample, 7 waves; wave = pool row; lane = out channel.
// Zero-padded 16x16 LDS word array (no bounds branches); pad contribution removed
// exactly via per-lane corrections; sliding 4x4 register window.
__global__ __launch_bounds__(448) void k2_conv2(const ULL* __restrict__ qact1,
        const ULL* __restrict__ wb2, const float* __restrict__ b2,
        const float* __restrict__ g, const float* __restrict__ be,
        const float* __restrict__ mu, const float* __restrict__ va,
        ULL* __restrict__ qact2) {
    __shared__ ULL ap[16][16];
    int b = blockIdx.x, t = threadIdx.x;
    int pr = t >> 6, lane = t & 63;          // pr = pool row 0..6
    if (t < 256) ap[t >> 4][t & 15] = 0ULL;
    __syncthreads();
    if (t < 196) ap[1 + t / 14][1 + t % 14] = qact1[(size_t)b * 196 + t];

    // per-lane (= output channel) weights and constants
    ULL wk[9];
    #pragma unroll
    for (int k = 0; k < 9; ++k) wk[k] = wb2[lane * 9 + k];
    int pw[9];
    #pragma unroll
    for (int k = 0; k < 9; ++k) pw[k] = 64 - 2 * (int)__popcll(wk[k]);
    double iv   = (double)g[lane] / sqrt((double)va[lane] + 1e-5);
    double cc   = (double)be[lane] - (double)mu[lane] * iv;
    double bias = (double)b2[lane];

    // padding corrections: corr[j][cls], j = conv-row within pool pair, cls 0=L,1=M,2=R
    int corr[2][3];
    #pragma unroll
    for (int j = 0; j < 2; ++j) {
        bool tpad = (pr == 0 && j == 0);
        bool bpad = (pr == 6 && j == 1);
        #pragma unroll
        for (int cls = 0; cls < 3; ++cls) {
            int cacc = 0;
            #pragma unroll
            for (int r = 0; r < 3; ++r) {
                #pragma unroll
                for (int k = 0; k < 3; ++k) {
                    bool pad = (r == 0 && tpad) || (r == 2 && bpad) ||
                               (k == 0 && cls == 0) || (k == 2 && cls == 2);
                    if (pad) cacc += pw[r * 3 + k];
                }
            }
            corr[j][cls] = cacc;
        }
    }
    __syncthreads();

    // sliding window: win[r][c] = ap[2*pr + r][2*px + c]
    ULL win[4][4];
    #pragma unroll
    for (int r = 0; r < 4; ++r) {
        win[r][0] = ap[2 * pr + r][0];
        win[r][1] = ap[2 * pr + r][1];
    }
    for (int px = 0; px < 7; ++px) {
        #pragma unroll
        for (int r = 0; r < 4; ++r) {
            win[r][2] = ap[2 * pr + r][2 * px + 2];
            win[r][3] = ap[2 * pr + r][2 * px + 3];
        }
        int s00 = 0, s01 = 0, s10 = 0, s11 = 0;
        #pragma unroll
        for (int r = 0; r < 3; ++r) {
            #pragma unroll
            for (int k = 0; k < 3; ++k) {
                ULL w = wk[r * 3 + k];
                s00 += (int)__popcll(win[r][k]         ^ w);
                s01 += (int)__popcll(win[r][k + 1]     ^ w);
                s10 += (int)__popcll(win[r + 1][k]     ^ w);
                s11 += (int)__popcll(win[r + 1][k + 1] ^ w);
            }
        }
        int clsL = (px == 0) ? 0 : 1, clsR = (px == 6) ? 2 : 1;
        int d00 = 576 - 2 * s00 - corr[0][clsL];
        int d01 = 576 - 2 * s01 - corr[0][clsR];
        int d10 = 576 - 2 * s10 - corr[1][clsL];
        int d11 = 576 - 2 * s11 - corr[1][clsR];
        int m = max(max(d00, d01), max(d10, d11));
        double tt = ((double)m + bias) * iv + cc;
        ULL word = __ballot(tt >= 0.0);
        if (lane == 0) qact2[(size_t)b * 49 + pr * 7 + px] = word;
        #pragma unroll
        for (int r = 0; r < 4; ++r) {
            win[r][0] = win[r][2];
            win[r][1] = win[r][3];
        }
    }
}

// ---------------- k3: fc1 + bn3 + binarize -> hbits ----------------
// block = 16 samples x 4 n-groups (wave = 64 outputs), weights reused 16x from L2
__global__ __launch_bounds__(256) void k3_fc1(const ULL* __restrict__ qact2,
        const ULL* __restrict__ wbT, const float* __restrict__ fb,
        const float* __restrict__ g, const float* __restrict__ be,
        const float* __restrict__ mu, const float* __restrict__ va,
        ULL* __restrict__ hbits) {
    __shared__ ULL xs[784];   // 16 samples x 49 words
    int t = threadIdx.x, wave = t >> 6, lane = t & 63;
    int b0 = blockIdx.x * 16;
    int gidx = blockIdx.y * 4 + wave;   // 0..31
    int n = gidx * 64 + lane;
    for (int i = t; i < 784; i += 256) xs[i] = qact2[(size_t)b0 * 49 + i];
    double iv   = (double)g[n] / sqrt((double)va[n] + 1e-5);
    double cc   = (double)be[n] - (double)mu[n] * iv;
    double bias = (double)fb[n];
    __syncthreads();
    int acc[16];
    #pragma unroll
    for (int i = 0; i < 16; ++i) acc[i] = 0;
    for (int p = 0; p < 49; ++p) {
        ULL w = wbT[p * 2048 + n];
        #pragma unroll
        for (int i = 0; i < 16; ++i)
            acc[i] += (int)__popcll(xs[i * 49 + p] ^ w);
    }
    #pragma unroll
    for (int i = 0; i < 16; ++i) {
        int dot = 3136 - 2 * acc[i];
        double tt = ((double)dot + bias) * iv + cc;
        ULL word = __ballot(tt >= 0.0);
        if (lane == 0) hbits[(size_t)(b0 + i) * 32 + gidx] = word;
    }
}

// ---------------- k4: fc2 + scale ----------------
__global__ __launch_bounds__(256) void k4_fc2(const ULL* __restrict__ hbits,
        const ULL* __restrict__ wbf2, const float* __restrict__ b2,
        const float* __restrict__ scale, float* __restrict__ out, int total) {
    int gid = blockIdx.x * 256 + threadIdx.x;
    if (gid >= total) return;
    int b = gid / 10, n = gid - b * 10;
    const ULL* h = hbits + (size_t)b * 32;
    const ULL* w = wbf2 + n * 32;
    int acc = 0;
    #pragma unroll
    for (int k = 0; k < 32; ++k) acc += (int)__popcll(h[k] ^ w[k]);
    int dot = 2048 - 2 * acc;
    double v = ((double)dot + (double)b2[n]) * (double)scale[0];
    out[gid] = (float)v;
}

// ---------------- launch ----------------
extern "C" void kernel_launch(void* const* d_in, const int* in_sizes, int n_in,
                              void* d_out, int out_size, void* d_ws, size_t ws_size,
                              hipStream_t stream) {
    const float* x      = (const float*)d_in[0];
    const float* w1     = (const float*)d_in[1];
    const float* b1     = (const float*)d_in[2];
    const float* w2     = (const float*)d_in[3];
    const float* b2     = (const float*)d_in[4];
    const float* fc1w   = (const float*)d_in[5];
    const float* fc1b   = (const float*)d_in[6];
    const float* fc2w   = (const float*)d_in[7];
    const float* fc2b   = (const float*)d_in[8];
    const float* g1 = (const float*)d_in[9],  *be1 = (const float*)d_in[10],
               *mu1 = (const float*)d_in[11], *va1 = (const float*)d_in[12];
    const float* g2 = (const float*)d_in[13], *be2 = (const float*)d_in[14],
               *mu2 = (const float*)d_in[15], *va2 = (const float*)d_in[16];
    const float* g3 = (const float*)d_in[17], *be3 = (const float*)d_in[18],
               *mu3 = (const float*)d_in[19], *va3 = (const float*)d_in[20];
    const float* scale = (const float*)d_in[21];
    float* out = (float*)d_out;

    int B = in_sizes[0] / 784;   // 4096

    // workspace layout (8B aligned)
    char* ws = (char*)d_ws;
    ULL* qact1 = (ULL*)(ws);                              // B*196 words
    ULL* qact2 = (ULL*)(ws + (size_t)B * 196 * 8);        // B*49 words
    ULL* hbits = (ULL*)(ws + (size_t)B * 245 * 8);        // B*32 words
    char* wsw  = ws + (size_t)B * 277 * 8;
    ULL* wb2   = (ULL*)(wsw);                             // 576 words
    ULL* wbT   = (ULL*)(wsw + 576 * 8);                   // 49*2048 words
    ULL* wbf2  = (ULL*)(wsw + 576 * 8 + 49 * 2048 * 8);   // 320 words
    float* sgn1 = (float*)(wsw + 576 * 8 + 49 * 2048 * 8 + 320 * 8); // 576 floats

    prep_sgn1<<<3, 256, 0, stream>>>(w1, sgn1);
    prep_pack_small<<<224, 256, 0, stream>>>(w2, fc2w, wb2, wbf2);
    prep_pack_fc1<<<512, 256, 0, stream>>>(fc1w, wbT);   // 512 blocks x 4 rows = 2048

    k1_conv1<<<B, 448, 0, stream>>>(x, sgn1, b1, g1, be1, mu1, va1, qact1);
    k2_conv2<<<B, 448, 0, stream>>>(qact1, wb2, b2, g2, be2, mu2, va2, qact2);
    k3_fc1<<<dim3(B / 16, 8), 256, 0, stream>>>(qact2, wbT, fc1b, g3, be3, mu3, va3, hbits);
    int total = B * 10;
    k4_fc2<<<(total + 255) / 256, 256, 0, stream>>>(hbits, wbf2, fc2b, scale, out, total);
}